// Round 10
// baseline (527.930 us; speedup 1.0000x reference)
//
#include <hip/hip_runtime.h>

#define DID 128
#define NCLS 8
#define NPB 512        // nodes per bucket (power of 2)
#define NPB_SHIFT 9
#define NBLK 256       // blocks in edge-partition phases
#define CAP 12288      // col staging capacity per bucket
#define PCHUNK 16      // pooling chunks per graph

typedef __attribute__((ext_vector_type(8))) short bf16x8;
typedef __attribute__((ext_vector_type(4))) float f32x4;
typedef __attribute__((ext_vector_type(8))) unsigned short u16x8;

static __device__ __forceinline__ unsigned short f2bf(float f) {
  union { float f; unsigned int u; } x;
  x.f = f;
  unsigned int r = (x.u + 0x7fffu + ((x.u >> 16) & 1u)) >> 16;  // RNE
  return (unsigned short)r;
}
static __device__ __forceinline__ float bfhi(unsigned int v) {
  union { unsigned int u; float f; } x;
  x.u = v & 0xffff0000u;
  return x.f;
}
static __device__ __forceinline__ float bflo(unsigned int v) {
  union { unsigned int u; float f; } x;
  x.u = v << 16;
  return x.f;
}
static __device__ __forceinline__ int lowerb(const int* __restrict__ a, int n,
                                             int key) {
  int lo = 0, hi = n;
  while (lo < hi) {
    int m = (lo + hi) >> 1;
    if (a[m] < key) lo = m + 1;
    else hi = m;
  }
  return lo;
}

// ---------------- kA: bucket hist (256 blk) | W pack (256 blk) | gsum zero
__global__ __launch_bounds__(256) void kA_hpz(
    const int* __restrict__ dst, int* __restrict__ hist, int E, int nbuk,
    const float* __restrict__ W0, const float* __restrict__ W1,
    const float* __restrict__ W2, const float* __restrict__ W3,
    unsigned short* __restrict__ P0, unsigned short* __restrict__ P1,
    unsigned short* __restrict__ P2, unsigned short* __restrict__ P3,
    float* __restrict__ gsum, int ngsum) {
  __shared__ int c[256];
  int bid = blockIdx.x, tid = threadIdx.x;
  if (bid < NBLK) {  // hist
    for (int i = tid; i < nbuk; i += 256) c[i] = 0;
    __syncthreads();
    int epb = (E + NBLK - 1) / NBLK;
    int e0 = bid * epb;
    int e1 = min(E, e0 + epb);
    for (int e = e0 + tid; e < e1; e += 256)
      atomicAdd(&c[dst[e] >> NPB_SHIFT], 1);
    __syncthreads();
    for (int i = tid; i < nbuk; i += 256)
      hist[(size_t)i * NBLK + bid] = c[i];
  } else if (bid < NBLK + 256) {  // pack 4 weight matrices
    int gid = (bid - NBLK) * 256 + tid;  // 0..65535
    int m = gid >> 14;
    int idx = gid & 16383;
    int j = idx & 7;
    int l = (idx >> 3) & 63;
    int kf = (idx >> 9) & 3;
    int ct = idx >> 11;
    int colc = ct * 16 + (l & 15);
    int k = kf * 32 + (l >> 4) * 8 + j;
    const float* W = (m == 0) ? W0 : (m == 1) ? W1 : (m == 2) ? W2 : W3;
    unsigned short* P = (m == 0) ? P0 : (m == 1) ? P1 : (m == 2) ? P2 : P3;
    P[idx] = f2bf(W[k * 128 + colc]);
  } else {  // zero gsum
    for (int i = tid; i < ngsum; i += 256) gsum[i] = 0.f;
  }
}

// ---------------- kB: block 0 = full exclusive scan of hist (nscan = nbuk*256,
// thread t owns segment [t*nbuk, (t+1)*nbuk)) | blocks 1.. = h fp32->bf16
__global__ __launch_bounds__(256) void kB_scan_h2b(
    const int* __restrict__ hist, int* __restrict__ boff, int nbuk, int E,
    const float* __restrict__ h, unsigned short* __restrict__ hb, int total8) {
  int tid = threadIdx.x;
  if (blockIdx.x == 0) {
    __shared__ int sd[256];
    int seg = nbuk;  // nscan / 256
    int base = tid * seg;
    int ssum = 0;
    for (int i = 0; i < seg; ++i) ssum += hist[base + i];
    sd[tid] = ssum;
    __syncthreads();
    for (int o = 1; o < 256; o <<= 1) {
      int x = (tid >= o) ? sd[tid - o] : 0;
      __syncthreads();
      sd[tid] += x;
      __syncthreads();
    }
    int run = sd[tid] - ssum;  // exclusive offset of this segment
    for (int i = 0; i < seg; ++i) {
      int v = hist[base + i];
      boff[base + i] = run;
      run += v;
    }
    if (tid == 255) boff[(size_t)nbuk * NBLK] = E;
  } else {
    int i = (blockIdx.x - 1) * 256 + tid;
    if (i >= total8) return;
    const float4* h4 = (const float4*)h;
    float4 a = h4[(size_t)i * 2];
    float4 b = h4[(size_t)i * 2 + 1];
    u16x8 o;
    o[0] = f2bf(a.x); o[1] = f2bf(a.y); o[2] = f2bf(a.z); o[3] = f2bf(a.w);
    o[4] = f2bf(b.x); o[5] = f2bf(b.y); o[6] = f2bf(b.z); o[7] = f2bf(b.w);
    *(u16x8*)(hb + (size_t)i * 8) = o;
  }
}

// ---------------- shared GEMM body (round-6 full-column form)
__device__ __forceinline__ void gemm_body(
    int bid, const unsigned short* __restrict__ hb,
    const unsigned short* __restrict__ WpS,
    const unsigned short* __restrict__ WpN, float* __restrict__ z,
    unsigned short* __restrict__ yb, int n) {
  const int l = threadIdx.x & 63;
  const int w = threadIdx.x >> 6;
  const int rowW = bid * 128 + w * 32;
  const int cl = l & 15;
  const int cg = l >> 4;

  bf16x8 A[2][4];
#pragma unroll
  for (int rt = 0; rt < 2; ++rt) {
    int row = rowW + rt * 16 + cl;
#pragma unroll
    for (int kf = 0; kf < 4; ++kf) {
      if (row < n)
        A[rt][kf] = *(const bf16x8*)(hb + (size_t)row * 128 + kf * 32 + cg * 8);
      else
        A[rt][kf] = (bf16x8){0, 0, 0, 0, 0, 0, 0, 0};
    }
  }

  f32x4 accS[2][8], accN[2][8];
#pragma unroll
  for (int rt = 0; rt < 2; ++rt)
#pragma unroll
    for (int ct = 0; ct < 8; ++ct) {
      accS[rt][ct] = (f32x4){0.f, 0.f, 0.f, 0.f};
      accN[rt][ct] = (f32x4){0.f, 0.f, 0.f, 0.f};
    }

#pragma unroll
  for (int ct = 0; ct < 8; ++ct) {
    bf16x8 BS[4], BN[4];
#pragma unroll
    for (int kf = 0; kf < 4; ++kf) {
      BS[kf] = *(const bf16x8*)(WpS + ((ct * 4 + kf) * 64 + l) * 8);
      BN[kf] = *(const bf16x8*)(WpN + ((ct * 4 + kf) * 64 + l) * 8);
    }
#pragma unroll
    for (int rt = 0; rt < 2; ++rt)
#pragma unroll
      for (int kf = 0; kf < 4; ++kf) {
        accS[rt][ct] =
            __builtin_amdgcn_mfma_f32_16x16x32_bf16(A[rt][kf], BS[kf], accS[rt][ct], 0, 0, 0);
        accN[rt][ct] =
            __builtin_amdgcn_mfma_f32_16x16x32_bf16(A[rt][kf], BN[kf], accN[rt][ct], 0, 0, 0);
      }
  }

#pragma unroll
  for (int rt = 0; rt < 2; ++rt)
#pragma unroll
    for (int ct = 0; ct < 8; ++ct) {
#pragma unroll
      for (int r = 0; r < 4; ++r) {
        int row = rowW + rt * 16 + cg * 4 + r;
        if (row < n) {
          int colc = ct * 16 + cl;
          z[(size_t)row * 128 + colc] = accS[rt][ct][r];
          yb[(size_t)row * 128 + colc] = f2bf(accN[rt][ct][r]);
        }
      }
    }
}

// ---------------- kC: CSR scatter (256 blk) | layer-1 GEMM (independent)
__global__ __launch_bounds__(256) void kC_scat_gemm(
    const int* __restrict__ src, const int* __restrict__ dst,
    const int* __restrict__ boff, unsigned int* __restrict__ pairs, int E,
    int nbuk, const unsigned short* __restrict__ hb,
    const unsigned short* __restrict__ WpS,
    const unsigned short* __restrict__ WpN, float* __restrict__ z,
    unsigned short* __restrict__ yb, int n) {
  int bid = blockIdx.x, tid = threadIdx.x;
  if (bid < NBLK) {
    __shared__ int cur[256];
    for (int i = tid; i < nbuk; i += 256)
      cur[i] = boff[(size_t)i * NBLK + bid];
    __syncthreads();
    int epb = (E + NBLK - 1) / NBLK;
    int e0 = bid * epb;
    int e1 = min(E, e0 + epb);
    for (int e = e0 + tid; e < e1; e += 256) {
      int s = src[e];
      int d = dst[e];
      int p = atomicAdd(&cur[d >> NPB_SHIFT], 1);
      pairs[p] = ((unsigned)(d & (NPB - 1)) << 23) | (unsigned)s;
    }
  } else {
    gemm_body(bid - NBLK, hb, WpS, WpN, z, yb, n);
  }
}

// ---------------- layer-2 GEMM (standalone)
__global__ __launch_bounds__(256, 2) void k_gemmS(
    const unsigned short* __restrict__ hb, const unsigned short* __restrict__ WpS,
    const unsigned short* __restrict__ WpN, float* __restrict__ z,
    unsigned short* __restrict__ yb, int n) {
  gemm_body(blockIdx.x, hb, WpS, WpN, z, yb, n);
}

// ---------------- bucketed CSR pass B: per-bucket build (512 thr)
__global__ __launch_bounds__(512) void kB_build(
    const unsigned int* __restrict__ pairs, const int* __restrict__ off,
    int* __restrict__ rp, int* __restrict__ col, int N, int nbuk, int E) {
  __shared__ int cnt[NPB];
  __shared__ int exc[NPB];
  __shared__ int colstage[CAP];
  int tid = threadIdx.x;
  int b = blockIdx.x;
  int eb = off[(size_t)b * NBLK];
  int ee = off[(size_t)(b + 1) * NBLK];
  int m = ee - eb;

  cnt[tid] = 0;
  __syncthreads();
  for (int i = eb + tid; i < ee; i += NPB) {
    int dl = (int)(pairs[i] >> 23);
    atomicAdd(&cnt[dl], 1);
  }
  __syncthreads();
  exc[tid] = cnt[tid];
  __syncthreads();
  for (int o = 1; o < NPB; o <<= 1) {
    int v = (tid >= o) ? exc[tid - o] : 0;
    __syncthreads();
    exc[tid] += v;
    __syncthreads();
  }
  int myexc = exc[tid] - cnt[tid];
  int node = b * NPB + tid;
  if (node < N) rp[node] = eb + myexc;
  if (b == nbuk - 1 && tid == 0) rp[N] = E;
  __syncthreads();
  cnt[tid] = myexc;  // cursor
  __syncthreads();
  if (m <= CAP) {
    for (int i = eb + tid; i < ee; i += NPB) {
      unsigned int pr = pairs[i];
      int dl = (int)(pr >> 23);
      int s = (int)(pr & 0x7fffffu);
      int p = atomicAdd(&cnt[dl], 1);
      colstage[p] = s;
    }
    __syncthreads();
    for (int i = tid; i < m; i += NPB) col[eb + i] = colstage[i];
  } else {
    for (int i = eb + tid; i < ee; i += NPB) {
      unsigned int pr = pairs[i];
      int dl = (int)(pr >> 23);
      int s = (int)(pr & 0x7fffffu);
      int p = atomicAdd(&cnt[dl], 1);
      col[eb + p] = s;
    }
  }
}

// ---------------- aggregation (round-6/8 form, unchanged)
template <int OUTMODE>
__global__ __launch_bounds__(256, 8) void k_aggr2(
    const unsigned int* __restrict__ Y, const float* Z,
    const int* __restrict__ rp, const int* __restrict__ col,
    const float* __restrict__ bias, void* outp, int n) {
  int wid = (blockIdx.x * 256 + threadIdx.x) >> 6;
  int lane = threadIdx.x & 63;
  if (wid >= n) return;
  int s = rp[wid], e = rp[wid + 1];
  float ax = 0.f, ay = 0.f;
  int i = s;
  for (; i + 8 <= e; i += 8) {
    unsigned int v0 = Y[(size_t)col[i + 0] * 64 + lane];
    unsigned int v1 = Y[(size_t)col[i + 1] * 64 + lane];
    unsigned int v2 = Y[(size_t)col[i + 2] * 64 + lane];
    unsigned int v3 = Y[(size_t)col[i + 3] * 64 + lane];
    unsigned int v4 = Y[(size_t)col[i + 4] * 64 + lane];
    unsigned int v5 = Y[(size_t)col[i + 5] * 64 + lane];
    unsigned int v6 = Y[(size_t)col[i + 6] * 64 + lane];
    unsigned int v7 = Y[(size_t)col[i + 7] * 64 + lane];
    ax += bflo(v0) + bflo(v1) + bflo(v2) + bflo(v3) + bflo(v4) + bflo(v5) +
          bflo(v6) + bflo(v7);
    ay += bfhi(v0) + bfhi(v1) + bfhi(v2) + bfhi(v3) + bfhi(v4) + bfhi(v5) +
          bfhi(v6) + bfhi(v7);
  }
  for (; i + 4 <= e; i += 4) {
    unsigned int v0 = Y[(size_t)col[i + 0] * 64 + lane];
    unsigned int v1 = Y[(size_t)col[i + 1] * 64 + lane];
    unsigned int v2 = Y[(size_t)col[i + 2] * 64 + lane];
    unsigned int v3 = Y[(size_t)col[i + 3] * 64 + lane];
    ax += bflo(v0) + bflo(v1) + bflo(v2) + bflo(v3);
    ay += bfhi(v0) + bfhi(v1) + bfhi(v2) + bfhi(v3);
  }
  for (; i < e; ++i) {
    unsigned int v = Y[(size_t)col[i] * 64 + lane];
    ax += bflo(v);
    ay += bfhi(v);
  }
  int deg = e - s;
  float scale = 1.0f / (float)(deg > 1 ? deg : 1);
  float2 zv = ((const float2*)Z)[(size_t)wid * 64 + lane];
  float2 bb = ((const float2*)bias)[lane];
  float ox = zv.x + ax * scale + bb.x;
  float oy = zv.y + ay * scale + bb.y;
  if (OUTMODE == 1) {
    ox = fmaxf(ox, 0.f);
    oy = fmaxf(oy, 0.f);
    unsigned int packed = (unsigned int)f2bf(ox) | ((unsigned int)f2bf(oy) << 16);
    ((unsigned int*)outp)[(size_t)wid * 64 + lane] = packed;
  } else {
    ((float2*)outp)[(size_t)wid * 64 + lane] = make_float2(ox, oy);
  }
}

// ---------------- kF: pool (all blocks) + head (block 0 after arrive-exit)
__global__ __launch_bounds__(256) void kF_pool_head(
    const float* __restrict__ H2, const int* __restrict__ gids,
    float* __restrict__ gsum, const float* __restrict__ perm,
    const float* __restrict__ Wc, const float* __restrict__ bc,
    float* __restrict__ out, int N, int NG, int* __restrict__ sync) {
  int bid = blockIdx.x, t = threadIdx.x;
  int g = bid / PCHUNK;
  int c = bid % PCHUNK;
  int s = lowerb(gids, N, g);
  int e = lowerb(gids, N, g + 1);
  int cnt = e - s;
  int per = (cnt + PCHUNK - 1) / PCHUNK;
  int rs = s + c * per;
  int re = rs + per < e ? rs + per : e;
  __shared__ float4 sacc[256];
  if (rs < re) {
    int rslot = t >> 5;
    int d4 = t & 31;
    const float4* H4 = (const float4*)H2;
    float4 acc = make_float4(0.f, 0.f, 0.f, 0.f);
    for (int r = rs + rslot; r < re; r += 8) {
      float4 v = H4[(size_t)r * 32 + d4];
      acc.x += v.x; acc.y += v.y; acc.z += v.z; acc.w += v.w;
    }
    sacc[t] = acc;
    __syncthreads();
#pragma unroll
    for (int o = 4; o >= 1; o >>= 1) {
      if (rslot < o) {
        float4 a = sacc[t];
        float4 b = sacc[t + o * 32];
        a.x += b.x; a.y += b.y; a.z += b.z; a.w += b.w;
        sacc[t] = a;
      }
      __syncthreads();
    }
    if (t < 32) {
      float4 a = sacc[t];
      atomicAdd(&gsum[g * DID + t * 4 + 0], a.x);
      atomicAdd(&gsum[g * DID + t * 4 + 1], a.y);
      atomicAdd(&gsum[g * DID + t * 4 + 2], a.z);
      atomicAdd(&gsum[g * DID + t * 4 + 3], a.w);
    }
  }
  __syncthreads();
  if (t == 0) {
    __threadfence();
    __hip_atomic_fetch_add(&sync[3], 1, __ATOMIC_ACQ_REL,
                           __HIP_MEMORY_SCOPE_AGENT);
  }
  if (bid != 0) return;
  if (t == 0) {
    while (__hip_atomic_load(&sync[3], __ATOMIC_ACQUIRE,
                             __HIP_MEMORY_SCOPE_AGENT) < (int)gridDim.x) {
      __builtin_amdgcn_s_sleep(4);
    }
    __threadfence();
  }
  __syncthreads();
  for (int idx = t; idx < NG * NCLS; idx += 256) {
    int gg = idx >> 3, cc = idx & 7;
    int gcnt = lowerb(gids, N, gg + 1) - lowerb(gids, N, gg);
    float inv = 1.0f / (float)(gcnt > 1 ? gcnt : 1);
    float acc = bc[cc];
#pragma unroll 4
    for (int k = 0; k < DID; ++k)
      acc += __hip_atomic_load(&gsum[gg * DID + k], __ATOMIC_RELAXED,
                               __HIP_MEMORY_SCOPE_AGENT) *
             inv * Wc[k * NCLS + cc];
#pragma unroll 4
    for (int k = 0; k < DID; ++k)
      acc += perm[gg * DID + k] * Wc[(DID + k) * NCLS + cc];
    out[gg * NCLS + cc] = acc;
  }
}

// ---------------------------------------------------------------- launch
extern "C" void kernel_launch(void* const* d_in, const int* in_sizes, int n_in,
                              void* d_out, int out_size, void* d_ws,
                              size_t ws_size, hipStream_t stream) {
  const float* h = (const float*)d_in[0];
  const float* perm = (const float*)d_in[1];
  const int* src = (const int*)d_in[2];
  const int* dst = (const int*)d_in[3];
  const int* gids = (const int*)d_in[4];
  const float* W1s = (const float*)d_in[5];
  const float* W1n = (const float*)d_in[6];
  const float* b1 = (const float*)d_in[7];
  const float* W2s = (const float*)d_in[8];
  const float* W2n = (const float*)d_in[9];
  const float* b2 = (const float*)d_in[10];
  const float* Wc = (const float*)d_in[11];
  const float* bc = (const float*)d_in[12];
  float* out = (float*)d_out;

  const int N = in_sizes[0] / DID;
  const int E = in_sizes[2];
  const int NG = in_sizes[1] / DID;
  const int nbuk = (N + NPB - 1) >> NPB_SHIFT;  // 196
  const int nscan = nbuk * NBLK;

  char* w = (char*)d_ws;
  size_t off_ = 0;
  auto alloc = [&](size_t bytes) -> void* {
    off_ = (off_ + 511) & ~(size_t)511;
    void* p = w + off_;
    off_ += bytes;
    return p;
  };
  int* sync = (int*)alloc(8 * 4);
  float* gsum = (float*)alloc((size_t)NG * DID * 4);
  int* hist = (int*)alloc((size_t)nscan * 4);
  int* boff = (int*)alloc((size_t)(nscan + 1) * 4);
  int* rp = (int*)alloc((size_t)(N + 1) * 4);
  int* col = (int*)alloc((size_t)E * 4);
  unsigned int* pairs = (unsigned int*)alloc((size_t)E * 4);
  unsigned short* hb = (unsigned short*)alloc((size_t)N * DID * 2);
  unsigned short* yb = (unsigned short*)alloc((size_t)N * DID * 2);
  float* z = (float*)alloc((size_t)N * DID * 4);
  unsigned short* Wp1s = (unsigned short*)alloc(128 * 128 * 2);
  unsigned short* Wp1n = (unsigned short*)alloc(128 * 128 * 2);
  unsigned short* Wp2s = (unsigned short*)alloc(128 * 128 * 2);
  unsigned short* Wp2n = (unsigned short*)alloc(128 * 128 * 2);

  const int ngb = (N + 127) / 128;
  const int nagg = (N + 3) / 4;
  const int total8 = N * DID / 8;
  const int ncvt = (total8 + 255) / 256;

  hipMemsetAsync(sync, 0, 8 * 4, stream);

  // kA: hist | pack | gsum-zero (independent phases)
  kA_hpz<<<NBLK + 256 + 1, 256, 0, stream>>>(dst, hist, E, nbuk, W1s, W1n, W2s,
                                             W2n, Wp1s, Wp1n, Wp2s, Wp2n, gsum,
                                             NG * DID);
  // kB: scan (1 block) | h->bf16 (ncvt blocks) — convert hides the scan
  kB_scan_h2b<<<1 + ncvt, 256, 0, stream>>>(hist, boff, nbuk, E, h, hb, total8);
  // kC: scatter | layer-1 GEMM (independent, concurrent)
  kC_scat_gemm<<<NBLK + ngb, 256, 0, stream>>>(src, dst, boff, pairs, E, nbuk,
                                               hb, Wp1s, Wp1n, z, yb, N);
  // build per-bucket CSR
  kB_build<<<nbuk, NPB, 0, stream>>>(pairs, boff, rp, col, N, nbuk, E);
  // layer 1 aggregation -> h1 bf16 (into hb)
  k_aggr2<1><<<nagg, 256, 0, stream>>>((const unsigned int*)yb, z, rp, col, b1,
                                       (void*)hb, N);
  // layer 2 GEMM
  k_gemmS<<<ngb, 256, 0, stream>>>(hb, Wp2s, Wp2n, z, yb, N);
  // layer 2 aggregation -> h2 fp32 (in-place in z)
  k_aggr2<0><<<nagg, 256, 0, stream>>>((const unsigned int*)yb, z, rp, col, b2,
                                       (void*)z, N);
  // pool + head fused
  kF_pool_head<<<NG * PCHUNK, 256, 0, stream>>>(z, gids, gsum, perm, Wc, bc,
                                                out, N, NG, sync);
}

// Round 11
// 488.853 us; speedup vs baseline: 1.0799x; 1.0799x over previous
//
#include <hip/hip_runtime.h>

#define DID 128
#define NCLS 8
#define NPB 512        // nodes per bucket (power of 2)
#define NPB_SHIFT 9
#define NBLK 256       // blocks in edge-partition phases
#define CAP 12288      // col staging capacity per bucket
#define PCHUNK 64      // pooling chunks per graph (4096 blocks: proven fast)

typedef __attribute__((ext_vector_type(8))) short bf16x8;
typedef __attribute__((ext_vector_type(4))) float f32x4;
typedef __attribute__((ext_vector_type(8))) unsigned short u16x8;

static __device__ __forceinline__ unsigned short f2bf(float f) {
  union { float f; unsigned int u; } x;
  x.f = f;
  unsigned int r = (x.u + 0x7fffu + ((x.u >> 16) & 1u)) >> 16;  // RNE
  return (unsigned short)r;
}
static __device__ __forceinline__ float bfhi(unsigned int v) {
  union { unsigned int u; float f; } x;
  x.u = v & 0xffff0000u;
  return x.f;
}
static __device__ __forceinline__ float bflo(unsigned int v) {
  union { unsigned int u; float f; } x;
  x.u = v << 16;
  return x.f;
}
static __device__ __forceinline__ int lowerb(const int* __restrict__ a, int n,
                                             int key) {
  int lo = 0, hi = n;
  while (lo < hi) {
    int m = (lo + hi) >> 1;
    if (a[m] < key) lo = m + 1;
    else hi = m;
  }
  return lo;
}

// ---------------- kA: bucket hist (256 blk) | W pack (256 blk) | gsum zero
__global__ __launch_bounds__(256) void kA_hpz(
    const int* __restrict__ dst, int* __restrict__ hist, int E, int nbuk,
    const float* __restrict__ W0, const float* __restrict__ W1,
    const float* __restrict__ W2, const float* __restrict__ W3,
    unsigned short* __restrict__ P0, unsigned short* __restrict__ P1,
    unsigned short* __restrict__ P2, unsigned short* __restrict__ P3,
    float* __restrict__ gsum, int ngsum) {
  __shared__ int c[256];
  int bid = blockIdx.x, tid = threadIdx.x;
  if (bid < NBLK) {  // hist
    for (int i = tid; i < nbuk; i += 256) c[i] = 0;
    __syncthreads();
    int epb = (E + NBLK - 1) / NBLK;
    int e0 = bid * epb;
    int e1 = min(E, e0 + epb);
    for (int e = e0 + tid; e < e1; e += 256)
      atomicAdd(&c[dst[e] >> NPB_SHIFT], 1);
    __syncthreads();
    for (int i = tid; i < nbuk; i += 256)
      hist[(size_t)i * NBLK + bid] = c[i];
  } else if (bid < NBLK + 256) {  // pack 4 weight matrices
    int gid = (bid - NBLK) * 256 + tid;  // 0..65535
    int m = gid >> 14;
    int idx = gid & 16383;
    int j = idx & 7;
    int l = (idx >> 3) & 63;
    int kf = (idx >> 9) & 3;
    int ct = idx >> 11;
    int colc = ct * 16 + (l & 15);
    int k = kf * 32 + (l >> 4) * 8 + j;
    const float* W = (m == 0) ? W0 : (m == 1) ? W1 : (m == 2) ? W2 : W3;
    unsigned short* P = (m == 0) ? P0 : (m == 1) ? P1 : (m == 2) ? P2 : P3;
    P[idx] = f2bf(W[k * 128 + colc]);
  } else {  // zero gsum
    for (int i = tid; i < ngsum; i += 256) gsum[i] = 0.f;
  }
}

// ---------------- kB: block 0 = full exclusive scan of hist (nscan = nbuk*256,
// thread t owns segment [t*nbuk, (t+1)*nbuk)) | blocks 1.. = h fp32->bf16
__global__ __launch_bounds__(256) void kB_scan_h2b(
    const int* __restrict__ hist, int* __restrict__ boff, int nbuk, int E,
    const float* __restrict__ h, unsigned short* __restrict__ hb, int total8) {
  int tid = threadIdx.x;
  if (blockIdx.x == 0) {
    __shared__ int sd[256];
    int seg = nbuk;  // nscan / 256
    int base = tid * seg;
    int ssum = 0;
    for (int i = 0; i < seg; ++i) ssum += hist[base + i];
    sd[tid] = ssum;
    __syncthreads();
    for (int o = 1; o < 256; o <<= 1) {
      int x = (tid >= o) ? sd[tid - o] : 0;
      __syncthreads();
      sd[tid] += x;
      __syncthreads();
    }
    int run = sd[tid] - ssum;  // exclusive offset of this segment
    for (int i = 0; i < seg; ++i) {
      int v = hist[base + i];
      boff[base + i] = run;
      run += v;
    }
    if (tid == 255) boff[(size_t)nbuk * NBLK] = E;
  } else {
    int i = (blockIdx.x - 1) * 256 + tid;
    if (i >= total8) return;
    const float4* h4 = (const float4*)h;
    float4 a = h4[(size_t)i * 2];
    float4 b = h4[(size_t)i * 2 + 1];
    u16x8 o;
    o[0] = f2bf(a.x); o[1] = f2bf(a.y); o[2] = f2bf(a.z); o[3] = f2bf(a.w);
    o[4] = f2bf(b.x); o[5] = f2bf(b.y); o[6] = f2bf(b.z); o[7] = f2bf(b.w);
    *(u16x8*)(hb + (size_t)i * 8) = o;
  }
}

// ---------------- shared GEMM body (round-6 full-column form)
__device__ __forceinline__ void gemm_body(
    int bid, const unsigned short* __restrict__ hb,
    const unsigned short* __restrict__ WpS,
    const unsigned short* __restrict__ WpN, float* __restrict__ z,
    unsigned short* __restrict__ yb, int n) {
  const int l = threadIdx.x & 63;
  const int w = threadIdx.x >> 6;
  const int rowW = bid * 128 + w * 32;
  const int cl = l & 15;
  const int cg = l >> 4;

  bf16x8 A[2][4];
#pragma unroll
  for (int rt = 0; rt < 2; ++rt) {
    int row = rowW + rt * 16 + cl;
#pragma unroll
    for (int kf = 0; kf < 4; ++kf) {
      if (row < n)
        A[rt][kf] = *(const bf16x8*)(hb + (size_t)row * 128 + kf * 32 + cg * 8);
      else
        A[rt][kf] = (bf16x8){0, 0, 0, 0, 0, 0, 0, 0};
    }
  }

  f32x4 accS[2][8], accN[2][8];
#pragma unroll
  for (int rt = 0; rt < 2; ++rt)
#pragma unroll
    for (int ct = 0; ct < 8; ++ct) {
      accS[rt][ct] = (f32x4){0.f, 0.f, 0.f, 0.f};
      accN[rt][ct] = (f32x4){0.f, 0.f, 0.f, 0.f};
    }

#pragma unroll
  for (int ct = 0; ct < 8; ++ct) {
    bf16x8 BS[4], BN[4];
#pragma unroll
    for (int kf = 0; kf < 4; ++kf) {
      BS[kf] = *(const bf16x8*)(WpS + ((ct * 4 + kf) * 64 + l) * 8);
      BN[kf] = *(const bf16x8*)(WpN + ((ct * 4 + kf) * 64 + l) * 8);
    }
#pragma unroll
    for (int rt = 0; rt < 2; ++rt)
#pragma unroll
      for (int kf = 0; kf < 4; ++kf) {
        accS[rt][ct] =
            __builtin_amdgcn_mfma_f32_16x16x32_bf16(A[rt][kf], BS[kf], accS[rt][ct], 0, 0, 0);
        accN[rt][ct] =
            __builtin_amdgcn_mfma_f32_16x16x32_bf16(A[rt][kf], BN[kf], accN[rt][ct], 0, 0, 0);
      }
  }

#pragma unroll
  for (int rt = 0; rt < 2; ++rt)
#pragma unroll
    for (int ct = 0; ct < 8; ++ct) {
#pragma unroll
      for (int r = 0; r < 4; ++r) {
        int row = rowW + rt * 16 + cg * 4 + r;
        if (row < n) {
          int colc = ct * 16 + cl;
          z[(size_t)row * 128 + colc] = accS[rt][ct][r];
          yb[(size_t)row * 128 + colc] = f2bf(accN[rt][ct][r]);
        }
      }
    }
}

// ---------------- kC: CSR scatter (256 blk) | layer-1 GEMM (independent)
__global__ __launch_bounds__(256) void kC_scat_gemm(
    const int* __restrict__ src, const int* __restrict__ dst,
    const int* __restrict__ boff, unsigned int* __restrict__ pairs, int E,
    int nbuk, const unsigned short* __restrict__ hb,
    const unsigned short* __restrict__ WpS,
    const unsigned short* __restrict__ WpN, float* __restrict__ z,
    unsigned short* __restrict__ yb, int n) {
  int bid = blockIdx.x, tid = threadIdx.x;
  if (bid < NBLK) {
    __shared__ int cur[256];
    for (int i = tid; i < nbuk; i += 256)
      cur[i] = boff[(size_t)i * NBLK + bid];
    __syncthreads();
    int epb = (E + NBLK - 1) / NBLK;
    int e0 = bid * epb;
    int e1 = min(E, e0 + epb);
    for (int e = e0 + tid; e < e1; e += 256) {
      int s = src[e];
      int d = dst[e];
      int p = atomicAdd(&cur[d >> NPB_SHIFT], 1);
      pairs[p] = ((unsigned)(d & (NPB - 1)) << 23) | (unsigned)s;
    }
  } else {
    gemm_body(bid - NBLK, hb, WpS, WpN, z, yb, n);
  }
}

// ---------------- layer-2 GEMM (standalone)
__global__ __launch_bounds__(256, 2) void k_gemmS(
    const unsigned short* __restrict__ hb, const unsigned short* __restrict__ WpS,
    const unsigned short* __restrict__ WpN, float* __restrict__ z,
    unsigned short* __restrict__ yb, int n) {
  gemm_body(blockIdx.x, hb, WpS, WpN, z, yb, n);
}

// ---------------- bucketed CSR pass B: per-bucket build (512 thr)
__global__ __launch_bounds__(512) void kB_build(
    const unsigned int* __restrict__ pairs, const int* __restrict__ off,
    int* __restrict__ rp, int* __restrict__ col, int N, int nbuk, int E) {
  __shared__ int cnt[NPB];
  __shared__ int exc[NPB];
  __shared__ int colstage[CAP];
  int tid = threadIdx.x;
  int b = blockIdx.x;
  int eb = off[(size_t)b * NBLK];
  int ee = off[(size_t)(b + 1) * NBLK];
  int m = ee - eb;

  cnt[tid] = 0;
  __syncthreads();
  for (int i = eb + tid; i < ee; i += NPB) {
    int dl = (int)(pairs[i] >> 23);
    atomicAdd(&cnt[dl], 1);
  }
  __syncthreads();
  exc[tid] = cnt[tid];
  __syncthreads();
  for (int o = 1; o < NPB; o <<= 1) {
    int v = (tid >= o) ? exc[tid - o] : 0;
    __syncthreads();
    exc[tid] += v;
    __syncthreads();
  }
  int myexc = exc[tid] - cnt[tid];
  int node = b * NPB + tid;
  if (node < N) rp[node] = eb + myexc;
  if (b == nbuk - 1 && tid == 0) rp[N] = E;
  __syncthreads();
  cnt[tid] = myexc;  // cursor
  __syncthreads();
  if (m <= CAP) {
    for (int i = eb + tid; i < ee; i += NPB) {
      unsigned int pr = pairs[i];
      int dl = (int)(pr >> 23);
      int s = (int)(pr & 0x7fffffu);
      int p = atomicAdd(&cnt[dl], 1);
      colstage[p] = s;
    }
    __syncthreads();
    for (int i = tid; i < m; i += NPB) col[eb + i] = colstage[i];
  } else {
    for (int i = eb + tid; i < ee; i += NPB) {
      unsigned int pr = pairs[i];
      int dl = (int)(pr >> 23);
      int s = (int)(pr & 0x7fffffu);
      int p = atomicAdd(&cnt[dl], 1);
      col[eb + p] = s;
    }
  }
}

// ---------------- aggregation (round-6/8 form, unchanged)
template <int OUTMODE>
__global__ __launch_bounds__(256, 8) void k_aggr2(
    const unsigned int* __restrict__ Y, const float* Z,
    const int* __restrict__ rp, const int* __restrict__ col,
    const float* __restrict__ bias, void* outp, int n) {
  int wid = (blockIdx.x * 256 + threadIdx.x) >> 6;
  int lane = threadIdx.x & 63;
  if (wid >= n) return;
  int s = rp[wid], e = rp[wid + 1];
  float ax = 0.f, ay = 0.f;
  int i = s;
  for (; i + 8 <= e; i += 8) {
    unsigned int v0 = Y[(size_t)col[i + 0] * 64 + lane];
    unsigned int v1 = Y[(size_t)col[i + 1] * 64 + lane];
    unsigned int v2 = Y[(size_t)col[i + 2] * 64 + lane];
    unsigned int v3 = Y[(size_t)col[i + 3] * 64 + lane];
    unsigned int v4 = Y[(size_t)col[i + 4] * 64 + lane];
    unsigned int v5 = Y[(size_t)col[i + 5] * 64 + lane];
    unsigned int v6 = Y[(size_t)col[i + 6] * 64 + lane];
    unsigned int v7 = Y[(size_t)col[i + 7] * 64 + lane];
    ax += bflo(v0) + bflo(v1) + bflo(v2) + bflo(v3) + bflo(v4) + bflo(v5) +
          bflo(v6) + bflo(v7);
    ay += bfhi(v0) + bfhi(v1) + bfhi(v2) + bfhi(v3) + bfhi(v4) + bfhi(v5) +
          bfhi(v6) + bfhi(v7);
  }
  for (; i + 4 <= e; i += 4) {
    unsigned int v0 = Y[(size_t)col[i + 0] * 64 + lane];
    unsigned int v1 = Y[(size_t)col[i + 1] * 64 + lane];
    unsigned int v2 = Y[(size_t)col[i + 2] * 64 + lane];
    unsigned int v3 = Y[(size_t)col[i + 3] * 64 + lane];
    ax += bflo(v0) + bflo(v1) + bflo(v2) + bflo(v3);
    ay += bfhi(v0) + bfhi(v1) + bfhi(v2) + bfhi(v3);
  }
  for (; i < e; ++i) {
    unsigned int v = Y[(size_t)col[i] * 64 + lane];
    ax += bflo(v);
    ay += bfhi(v);
  }
  int deg = e - s;
  float scale = 1.0f / (float)(deg > 1 ? deg : 1);
  float2 zv = ((const float2*)Z)[(size_t)wid * 64 + lane];
  float2 bb = ((const float2*)bias)[lane];
  float ox = zv.x + ax * scale + bb.x;
  float oy = zv.y + ay * scale + bb.y;
  if (OUTMODE == 1) {
    ox = fmaxf(ox, 0.f);
    oy = fmaxf(oy, 0.f);
    unsigned int packed = (unsigned int)f2bf(ox) | ((unsigned int)f2bf(oy) << 16);
    ((unsigned int*)outp)[(size_t)wid * 64 + lane] = packed;
  } else {
    ((float2*)outp)[(size_t)wid * 64 + lane] = make_float2(ox, oy);
  }
}

// ---------------- pooling (round-8 proven form: 4096 blocks)
__global__ __launch_bounds__(256) void k_pool(const float* __restrict__ H2,
                                              const int* __restrict__ gids,
                                              float* __restrict__ gsum, int N) {
  int g = blockIdx.x / PCHUNK;
  int c = blockIdx.x % PCHUNK;
  int t = threadIdx.x;
  int s = lowerb(gids, N, g);
  int e = lowerb(gids, N, g + 1);
  int cnt = e - s;
  int per = (cnt + PCHUNK - 1) / PCHUNK;
  int rs = s + c * per;
  int re = rs + per < e ? rs + per : e;
  if (rs >= re) return;  // uniform per block
  int rslot = t >> 5;    // 0..7
  int d4 = t & 31;       // float4 index within row
  const float4* H4 = (const float4*)H2;
  float4 acc = make_float4(0.f, 0.f, 0.f, 0.f);
  for (int r = rs + rslot; r < re; r += 8) {
    float4 v = H4[(size_t)r * 32 + d4];
    acc.x += v.x; acc.y += v.y; acc.z += v.z; acc.w += v.w;
  }
  __shared__ float4 sacc[256];
  sacc[t] = acc;
  __syncthreads();
#pragma unroll
  for (int o = 4; o >= 1; o >>= 1) {
    if (rslot < o) {
      float4 a = sacc[t];
      float4 b = sacc[t + o * 32];
      a.x += b.x; a.y += b.y; a.z += b.z; a.w += b.w;
      sacc[t] = a;
    }
    __syncthreads();
  }
  if (t < 32) {
    float4 a = sacc[t];
    atomicAdd(&gsum[g * DID + t * 4 + 0], a.x);
    atomicAdd(&gsum[g * DID + t * 4 + 1], a.y);
    atomicAdd(&gsum[g * DID + t * 4 + 2], a.z);
    atomicAdd(&gsum[g * DID + t * 4 + 3], a.w);
  }
}

__global__ void k_head(const float* __restrict__ gsum,
                       const float* __restrict__ perm,
                       const float* __restrict__ Wc,
                       const float* __restrict__ bc,
                       const int* __restrict__ gids, float* __restrict__ out,
                       int N, int NG) {
  int t = threadIdx.x;
  if (t >= NG * NCLS) return;
  int g = t >> 3, c = t & 7;
  int cnt = lowerb(gids, N, g + 1) - lowerb(gids, N, g);
  float inv = 1.0f / (float)(cnt > 1 ? cnt : 1);
  float acc = bc[c];
#pragma unroll 4
  for (int k = 0; k < DID; ++k)
    acc += gsum[g * DID + k] * inv * Wc[k * NCLS + c];
#pragma unroll 4
  for (int k = 0; k < DID; ++k)
    acc += perm[g * DID + k] * Wc[(DID + k) * NCLS + c];
  out[g * NCLS + c] = acc;
}

// ---------------------------------------------------------------- launch
extern "C" void kernel_launch(void* const* d_in, const int* in_sizes, int n_in,
                              void* d_out, int out_size, void* d_ws,
                              size_t ws_size, hipStream_t stream) {
  const float* h = (const float*)d_in[0];
  const float* perm = (const float*)d_in[1];
  const int* src = (const int*)d_in[2];
  const int* dst = (const int*)d_in[3];
  const int* gids = (const int*)d_in[4];
  const float* W1s = (const float*)d_in[5];
  const float* W1n = (const float*)d_in[6];
  const float* b1 = (const float*)d_in[7];
  const float* W2s = (const float*)d_in[8];
  const float* W2n = (const float*)d_in[9];
  const float* b2 = (const float*)d_in[10];
  const float* Wc = (const float*)d_in[11];
  const float* bc = (const float*)d_in[12];
  float* out = (float*)d_out;

  const int N = in_sizes[0] / DID;
  const int E = in_sizes[2];
  const int NG = in_sizes[1] / DID;
  const int nbuk = (N + NPB - 1) >> NPB_SHIFT;  // 196
  const int nscan = nbuk * NBLK;

  char* w = (char*)d_ws;
  size_t off_ = 0;
  auto alloc = [&](size_t bytes) -> void* {
    off_ = (off_ + 511) & ~(size_t)511;
    void* p = w + off_;
    off_ += bytes;
    return p;
  };
  float* gsum = (float*)alloc((size_t)NG * DID * 4);
  int* hist = (int*)alloc((size_t)nscan * 4);
  int* boff = (int*)alloc((size_t)(nscan + 1) * 4);
  int* rp = (int*)alloc((size_t)(N + 1) * 4);
  int* col = (int*)alloc((size_t)E * 4);
  unsigned int* pairs = (unsigned int*)alloc((size_t)E * 4);
  unsigned short* hb = (unsigned short*)alloc((size_t)N * DID * 2);
  unsigned short* yb = (unsigned short*)alloc((size_t)N * DID * 2);
  float* z = (float*)alloc((size_t)N * DID * 4);
  unsigned short* Wp1s = (unsigned short*)alloc(128 * 128 * 2);
  unsigned short* Wp1n = (unsigned short*)alloc(128 * 128 * 2);
  unsigned short* Wp2s = (unsigned short*)alloc(128 * 128 * 2);
  unsigned short* Wp2n = (unsigned short*)alloc(128 * 128 * 2);

  const int ngb = (N + 127) / 128;
  const int nagg = (N + 3) / 4;
  const int total8 = N * DID / 8;
  const int ncvt = (total8 + 255) / 256;

  // kA: hist | pack | gsum-zero (independent phases)
  kA_hpz<<<NBLK + 256 + 1, 256, 0, stream>>>(dst, hist, E, nbuk, W1s, W1n, W2s,
                                             W2n, Wp1s, Wp1n, Wp2s, Wp2n, gsum,
                                             NG * DID);
  // kB: scan (1 block) | h->bf16 (ncvt blocks) — convert hides the scan
  kB_scan_h2b<<<1 + ncvt, 256, 0, stream>>>(hist, boff, nbuk, E, h, hb, total8);
  // kC: scatter | layer-1 GEMM (independent, concurrent)
  kC_scat_gemm<<<NBLK + ngb, 256, 0, stream>>>(src, dst, boff, pairs, E, nbuk,
                                               hb, Wp1s, Wp1n, z, yb, N);
  // build per-bucket CSR
  kB_build<<<nbuk, NPB, 0, stream>>>(pairs, boff, rp, col, N, nbuk, E);
  // layer 1 aggregation -> h1 bf16 (into hb)
  k_aggr2<1><<<nagg, 256, 0, stream>>>((const unsigned int*)yb, z, rp, col, b1,
                                       (void*)hb, N);
  // layer 2 GEMM
  k_gemmS<<<ngb, 256, 0, stream>>>(hb, Wp2s, Wp2n, z, yb, N);
  // layer 2 aggregation -> h2 fp32 (in-place in z)
  k_aggr2<0><<<nagg, 256, 0, stream>>>((const unsigned int*)yb, z, rp, col, b2,
                                       (void*)z, N);
  // readout
  k_pool<<<NG * PCHUNK, 256, 0, stream>>>(z, gids, gsum, N);
  k_head<<<1, 512, 0, stream>>>(gsum, perm, Wc, bc, gids, out, N, NG);
}